// Round 1
// baseline (127.503 us; speedup 1.0000x reference)
//
#include <hip/hip_runtime.h>

// CensusLoss = mean |census(pred)-census(target)| = mismatch_count / (8*48*512*512).
// R12 kernel — R7 structure + ballot/popcount scalar-pipe accumulation.
// Fused: gray-on-the-fly into column-major LDS halo, b128 window reads,
// wave-wide ballot mismatch count on the SALU, one atomic per block.
//
// Session ledger (why this exact shape):
//  - 64x32 tile, 512 threads, RPT=4, stage -> ONE sync -> ONE uniform compute
//    site. Divergent wave-split pipelines (R4-R6) spill 90-170B/thread to
//    scratch (WRITE_SIZE 44-47MB) and regress 1.6-2x. Banned.
//  - stageA/computeA sandwich overlap (R8): no gain (barrier drain is
//    structural), -2.6us. Banned.
//  - Symmetry-halving T=2*S+ + C (R9-R11): exact (absmax 0.0) but never
//    faster — compute is LDS/latency-bound, not compare-bound, and the
//    border-correction kernel adds a serialized launch. Banned.
//  - float4 interior staging + cbase swizzle (R7) is the one staging
//    upgrade that measured as a win (101.3 -> 98.8).
//  - R12 (this): per-neighbor (cmpP != cmpT) per-lane add chain replaced by
//    __builtin_amdgcn_ballot_w64 (single v_cmp, SGPR dest) + s_xor_b64 +
//    s_bcnt1 + s_add on the SCALAR pipe. Halves compute-phase VALU instrs,
//    deletes the 6-step shuffle reduce (cnt is wave-uniform).
// Remaining time: ~72us harness poison fills (fixed), ~10.5us HBM floor for
// the staged fetch, compute+latency on top.

#define BATCH 8
#define HH 512
#define WW 512
#define PLANE (HH * WW)
#define TW 64
#define TH 32
#define SCOLS 72          // staged cols: gx = tx0-4+lx (f4-aligned)
#define HROWS 38          // halo rows:  gy = ty0-3+hy
#define KPR 18            // float4 chunks per halo row (72/4)
#define PITCH 44
#define NT 512
#define LDSZ (SCOLS * PITCH)   // 3168 dwords; max index 71*44+4+37 = 3165

__device__ __forceinline__ int refl(int v, int n) {
    return v < 0 ? -v : (v >= n ? 2 * n - 2 - v : v);
}
__device__ __forceinline__ int cbase(int lx) {      // swizzled column base
    return lx * PITCH + (((lx >> 2) & 7) << 2);     // stays 0 mod 4 -> 16B cols
}

// Load 10 consecutive column floats (16B-aligned) into registers.
__device__ __forceinline__ void load_col10(const float* col, float (&w)[10]) {
    const float4 a = *(const float4*)(col);
    const float4 b = *(const float4*)(col + 4);
    const float2 d = *(const float2*)(col + 8);
    w[0] = a.x; w[1] = a.y; w[2] = a.z; w[3] = a.w;
    w[4] = b.x; w[5] = b.y; w[6] = b.z; w[7] = b.w;
    w[8] = d.x; w[9] = d.y;
}

// Wave-wide mismatch count for one (center, neighbor) pair across 64 lanes.
// Ballot lowers to a single v_cmp with SGPR dest; xor/popcount/add run on
// the scalar pipe, in parallel with VALU + LDS issue.
__device__ __forceinline__ int mism(float cp, float np, float ct, float nt_) {
    const unsigned long long bP = __builtin_amdgcn_ballot_w64(cp > np);
    const unsigned long long bT = __builtin_amdgcn_ballot_w64(ct > nt_);
    return __builtin_popcountll(bP ^ bT);
}

__global__ __launch_bounds__(NT, 8)
void census_fused(const float* __restrict__ pred,
                  const float* __restrict__ target,
                  float* __restrict__ out) {
    __shared__ __align__(16) float sP[LDSZ];
    __shared__ __align__(16) float sT[LDSZ];

    const int b   = blockIdx.z;
    const int ty0 = blockIdx.y * TH;
    const int tx0 = blockIdx.x * TW;
    const float* __restrict__ pb = pred   + (size_t)b * 3 * PLANE;
    const float* __restrict__ tb = target + (size_t)b * 3 * PLANE;
    const bool fastx = (blockIdx.x >= 1 && blockIdx.x <= 6);  // gx always in range

    // ---- stage full 72x38 halo, then one barrier ----
    if (fastx) {
        for (int idx = threadIdx.x; idx < HROWS * KPR; idx += NT) {
            const int hy = idx / KPR;
            const int k  = idx - hy * KPR;
            const int gy  = refl(ty0 + hy - 3, HH);
            const int off = gy * WW + tx0 - 4 + 4 * k;        // 16B-aligned
            const float4 pr = *(const float4*)(pb + off);
            const float4 pg = *(const float4*)(pb + off + PLANE);
            const float4 pc = *(const float4*)(pb + off + 2 * PLANE);
            const float4 tr = *(const float4*)(tb + off);
            const float4 tg = *(const float4*)(tb + off + PLANE);
            const float4 tc = *(const float4*)(tb + off + 2 * PLANE);
            const int lx = 4 * k;
            sP[cbase(lx + 0) + hy] = 0.299f * pr.x + 0.587f * pg.x + 0.114f * pc.x;
            sP[cbase(lx + 1) + hy] = 0.299f * pr.y + 0.587f * pg.y + 0.114f * pc.y;
            sP[cbase(lx + 2) + hy] = 0.299f * pr.z + 0.587f * pg.z + 0.114f * pc.z;
            sP[cbase(lx + 3) + hy] = 0.299f * pr.w + 0.587f * pg.w + 0.114f * pc.w;
            sT[cbase(lx + 0) + hy] = 0.299f * tr.x + 0.587f * tg.x + 0.114f * tc.x;
            sT[cbase(lx + 1) + hy] = 0.299f * tr.y + 0.587f * tg.y + 0.114f * tc.y;
            sT[cbase(lx + 2) + hy] = 0.299f * tr.z + 0.587f * tg.z + 0.114f * tc.z;
            sT[cbase(lx + 3) + hy] = 0.299f * tr.w + 0.587f * tg.w + 0.114f * tc.w;
        }
    } else {
        for (int idx = threadIdx.x; idx < HROWS * SCOLS; idx += NT) {
            const int hy = idx / SCOLS;
            const int lx = idx - hy * SCOLS;
            const int gy  = refl(ty0 + hy - 3, HH);
            const int gx  = refl(tx0 + lx - 4, WW);
            const int off = gy * WW + gx;
            sP[cbase(lx) + hy] = 0.299f * pb[off] + 0.587f * pb[off + PLANE] + 0.114f * pb[off + 2 * PLANE];
            sT[cbase(lx) + hy] = 0.299f * tb[off] + 0.587f * tb[off + PLANE] + 0.114f * tb[off + 2 * PLANE];
        }
    }
    __syncthreads();

    const int wv  = threadIdx.x >> 6;   // wave == 4-row band
    const int c   = threadIdx.x & 63;   // pixel column in tile
    const int pr0 = wv * 4;             // first pixel row (0,4,..,28); pr0 % 4 == 0

    // Pixel (tx0+c, ty0+pr0+p), p=0..3: center at col c+4, halo row pr0+3+p;
    // window cols lx = c+1..c+7, halo rows pr0..pr0+9. Single call site.
    // cnt is the WAVE-TOTAL mismatch count (uniform across lanes).
    float wP[10], wT[10], cP[4], cT[4];
    int cnt = 0;
    load_col10(&sP[cbase(c + 4) + pr0], wP);        // dx = 0 column (holds centers)
    load_col10(&sT[cbase(c + 4) + pr0], wT);
    #pragma unroll
    for (int p = 0; p < 4; ++p) { cP[p] = wP[3 + p]; cT[p] = wT[3 + p]; }
    #pragma unroll
    for (int p = 0; p < 4; ++p) {
        #pragma unroll
        for (int dy = -3; dy <= 3; ++dy) {
            if (dy == 0) continue;                  // skip center
            cnt += mism(cP[p], wP[3 + p + dy], cT[p], wT[3 + p + dy]);
        }
    }
    #pragma unroll
    for (int t = 0; t < 6; ++t) {
        const int lx = c + 1 + (t < 3 ? t : t + 1); // dx = -3..3, dx != 0
        load_col10(&sP[cbase(lx) + pr0], wP);
        load_col10(&sT[cbase(lx) + pr0], wT);
        #pragma unroll
        for (int p = 0; p < 4; ++p) {
            #pragma unroll
            for (int dy = -3; dy <= 3; ++dy)
                cnt += mism(cP[p], wP[3 + p + dy], cT[p], wT[3 + p + dy]);
        }
    }

    // cnt is already the wave total (ballot/popcount) — no shuffle reduce.
    __shared__ int wsum[8];
    if ((threadIdx.x & 63) == 0) wsum[wv] = cnt;
    __syncthreads();
    if (threadIdx.x == 0) {
        int tot = 0;
        #pragma unroll
        for (int w = 0; w < 8; ++w) tot += wsum[w];
        // N = 8 * 48 * 512 * 512 = 100663296
        atomicAdd(out, (float)tot * (1.0f / 100663296.0f));
    }
}

extern "C" void kernel_launch(void* const* d_in, const int* in_sizes, int n_in,
                              void* d_out, int out_size, void* d_ws, size_t ws_size,
                              hipStream_t stream) {
    const float* pred   = (const float*)d_in[0];
    const float* target = (const float*)d_in[1];
    float* out = (float*)d_out;

    hipMemsetAsync(out, 0, sizeof(float), stream);   // d_out poisoned 0xAA

    dim3 grid(WW / TW, HH / TH, BATCH);              // (8, 16, 8) = 1024 blocks
    census_fused<<<grid, NT, 0, stream>>>(pred, target, out);
}

// Round 2
// 99.613 us; speedup vs baseline: 1.2800x; 1.2800x over previous
//
#include <hip/hip_runtime.h>

// CensusLoss = mean |census(pred)-census(target)| = mismatch_count / (8*48*512*512).
// R13 kernel — R7 structure (per-lane predicated count) + RPT=8 / 64x64 tile.
// Fused: gray-on-the-fly into column-major LDS halo, b128 window reads,
// per-lane predicated mismatch count, shuffle reduce, one atomic per block.
//
// Session ledger (why this exact shape):
//  - stage -> ONE sync -> ONE uniform compute site. Divergent wave-split
//    pipelines (R4-R6) spill 90-170B/thread to scratch and regress 1.6-2x. Banned.
//  - stageA/computeA sandwich overlap (R8): no gain, -2.6us. Banned.
//  - Symmetry-halving T=2*S+C (R9-R11): exact but never faster. Banned.
//  - float4 interior staging + cbase swizzle (R7): measured win (101.3 -> 98.8).
//  - Ballot/popcount SALU accumulation (R12): census 26 -> 55us. The scalar
//    unit is CU-SHARED (1 per 4 SIMDs) and v_cmp->SGPR->SALU chains pay
//    hazard wait-states; wave-wide accumulation serializes the whole compute
//    stream. Banned.
//  - R13 (this): RPT 4 -> 8 (14-float column windows serve 8 pixel rows),
//    64x64 tile, 512 blocks. LDS reads/pixel 10.5 -> 7. PITCH=76 keeps the
//    same mod-32 residue (12) as R7's PITCH=44 -> identical bank structure.
// Remaining time: ~72us harness poison fills (fixed), ~10.5us HBM floor for
// the staged fetch, compute+latency on top.

#define BATCH 8
#define HH 512
#define WW 512
#define PLANE (HH * WW)
#define TW 64
#define TH 64
#define SCOLS 72          // staged cols: gx = tx0-4+lx (f4-aligned)
#define HROWS 70          // halo rows:  gy = ty0-3+hy
#define KPR 18            // float4 chunks per halo row (72/4)
#define PITCH 76          // 76 mod 32 == 12 == 44 mod 32 (same bank structure)
#define NT 512
#define LDSZ (SCOLS * PITCH)   // 5472 dwords; max index cbase(71)+69 = 5469

__device__ __forceinline__ int refl(int v, int n) {
    return v < 0 ? -v : (v >= n ? 2 * n - 2 - v : v);
}
__device__ __forceinline__ int cbase(int lx) {      // swizzled column base
    return lx * PITCH + (((lx >> 2) & 7) << 2);     // stays 0 mod 4 -> 16B cols
}

// Load 14 consecutive column floats (16B-aligned base) into registers.
__device__ __forceinline__ void load_col14(const float* col, float (&w)[14]) {
    const float4 a = *(const float4*)(col);
    const float4 b = *(const float4*)(col + 4);
    const float4 c = *(const float4*)(col + 8);
    const float2 d = *(const float2*)(col + 12);
    w[0]  = a.x; w[1]  = a.y; w[2]  = a.z; w[3]  = a.w;
    w[4]  = b.x; w[5]  = b.y; w[6]  = b.z; w[7]  = b.w;
    w[8]  = c.x; w[9]  = c.y; w[10] = c.z; w[11] = c.w;
    w[12] = d.x; w[13] = d.y;
}

__global__ __launch_bounds__(NT, 4)
void census_fused(const float* __restrict__ pred,
                  const float* __restrict__ target,
                  float* __restrict__ out) {
    __shared__ __align__(16) float sP[LDSZ];
    __shared__ __align__(16) float sT[LDSZ];

    const int b   = blockIdx.z;
    const int ty0 = blockIdx.y * TH;
    const int tx0 = blockIdx.x * TW;
    const float* __restrict__ pb = pred   + (size_t)b * 3 * PLANE;
    const float* __restrict__ tb = target + (size_t)b * 3 * PLANE;
    const bool fastx = (blockIdx.x >= 1 && blockIdx.x <= 6);  // gx always in range

    // ---- stage full 72x70 halo, then one barrier ----
    if (fastx) {
        for (int idx = threadIdx.x; idx < HROWS * KPR; idx += NT) {
            const int hy = idx / KPR;
            const int k  = idx - hy * KPR;
            const int gy  = refl(ty0 + hy - 3, HH);
            const int off = gy * WW + tx0 - 4 + 4 * k;        // 16B-aligned
            const float4 pr = *(const float4*)(pb + off);
            const float4 pg = *(const float4*)(pb + off + PLANE);
            const float4 pc = *(const float4*)(pb + off + 2 * PLANE);
            const float4 tr = *(const float4*)(tb + off);
            const float4 tg = *(const float4*)(tb + off + PLANE);
            const float4 tc = *(const float4*)(tb + off + 2 * PLANE);
            const int lx = 4 * k;
            sP[cbase(lx + 0) + hy] = 0.299f * pr.x + 0.587f * pg.x + 0.114f * pc.x;
            sP[cbase(lx + 1) + hy] = 0.299f * pr.y + 0.587f * pg.y + 0.114f * pc.y;
            sP[cbase(lx + 2) + hy] = 0.299f * pr.z + 0.587f * pg.z + 0.114f * pc.z;
            sP[cbase(lx + 3) + hy] = 0.299f * pr.w + 0.587f * pg.w + 0.114f * pc.w;
            sT[cbase(lx + 0) + hy] = 0.299f * tr.x + 0.587f * tg.x + 0.114f * tc.x;
            sT[cbase(lx + 1) + hy] = 0.299f * tr.y + 0.587f * tg.y + 0.114f * tc.y;
            sT[cbase(lx + 2) + hy] = 0.299f * tr.z + 0.587f * tg.z + 0.114f * tc.z;
            sT[cbase(lx + 3) + hy] = 0.299f * tr.w + 0.587f * tg.w + 0.114f * tc.w;
        }
    } else {
        for (int idx = threadIdx.x; idx < HROWS * SCOLS; idx += NT) {
            const int hy = idx / SCOLS;
            const int lx = idx - hy * SCOLS;
            const int gy  = refl(ty0 + hy - 3, HH);
            const int gx  = refl(tx0 + lx - 4, WW);
            const int off = gy * WW + gx;
            sP[cbase(lx) + hy] = 0.299f * pb[off] + 0.587f * pb[off + PLANE] + 0.114f * pb[off + 2 * PLANE];
            sT[cbase(lx) + hy] = 0.299f * tb[off] + 0.587f * tb[off + PLANE] + 0.114f * tb[off + 2 * PLANE];
        }
    }
    __syncthreads();

    const int wv  = threadIdx.x >> 6;   // wave == 8-row band
    const int c   = threadIdx.x & 63;   // pixel column in tile
    const int pr0 = wv * 8;             // first pixel row (0,8,..,56); pr0 % 4 == 0

    // Pixel (tx0+c, ty0+pr0+p), p=0..7: center at col c+4, halo row pr0+3+p;
    // window cols lx = c+1..c+7, halo rows pr0..pr0+13. Single call site.
    float wP[14], wT[14], cP[8], cT[8];
    int cnt = 0;
    load_col14(&sP[cbase(c + 4) + pr0], wP);        // dx = 0 column (holds centers)
    load_col14(&sT[cbase(c + 4) + pr0], wT);
    #pragma unroll
    for (int p = 0; p < 8; ++p) { cP[p] = wP[3 + p]; cT[p] = wT[3 + p]; }
    #pragma unroll
    for (int p = 0; p < 8; ++p) {
        #pragma unroll
        for (int dy = -3; dy <= 3; ++dy) {
            if (dy == 0) continue;                  // skip center
            cnt += ((cP[p] > wP[3 + p + dy]) != (cT[p] > wT[3 + p + dy])) ? 1 : 0;
        }
    }
    #pragma unroll
    for (int t = 0; t < 6; ++t) {
        const int lx = c + 1 + (t < 3 ? t : t + 1); // dx = -3..3, dx != 0
        load_col14(&sP[cbase(lx) + pr0], wP);
        load_col14(&sT[cbase(lx) + pr0], wT);
        #pragma unroll
        for (int p = 0; p < 8; ++p) {
            #pragma unroll
            for (int dy = -3; dy <= 3; ++dy)
                cnt += ((cP[p] > wP[3 + p + dy]) != (cT[p] > wT[3 + p + dy])) ? 1 : 0;
        }
    }

    // Reduce: 64-lane shuffle, cross-wave LDS, one atomic per block.
    #pragma unroll
    for (int o = 32; o > 0; o >>= 1) cnt += __shfl_down(cnt, o, 64);
    __shared__ int wsum[8];
    if ((threadIdx.x & 63) == 0) wsum[wv] = cnt;
    __syncthreads();
    if (threadIdx.x == 0) {
        int tot = 0;
        #pragma unroll
        for (int w = 0; w < 8; ++w) tot += wsum[w];
        // N = 8 * 48 * 512 * 512 = 100663296
        atomicAdd(out, (float)tot * (1.0f / 100663296.0f));
    }
}

extern "C" void kernel_launch(void* const* d_in, const int* in_sizes, int n_in,
                              void* d_out, int out_size, void* d_ws, size_t ws_size,
                              hipStream_t stream) {
    const float* pred   = (const float*)d_in[0];
    const float* target = (const float*)d_in[1];
    float* out = (float*)d_out;

    hipMemsetAsync(out, 0, sizeof(float), stream);   // d_out poisoned 0xAA

    dim3 grid(WW / TW, HH / TH, BATCH);              // (8, 8, 8) = 512 blocks
    census_fused<<<grid, NT, 0, stream>>>(pred, target, out);
}